// Round 4
// baseline (1579.554 us; speedup 1.0000x reference)
//
#include <hip/hip_runtime.h>

static constexpr int HID  = 4096;  // hidden size
static constexpr int SEQL = 40;
static constexpr int OUTN = 128;
static constexpr int NBLK = 256;   // 256 blocks x 1024 thr: 1 block/CU co-resident

// ---------- fp32 -> bf16 (RNE) ----------
__device__ __forceinline__ unsigned f2bf(float f) {
    unsigned u = __float_as_uint(f);
    return (u + 0x7fffu + ((u >> 16) & 1u)) >> 16;
}
__device__ __forceinline__ unsigned pack2(float lo, float hi) {
    return f2bf(lo) | (f2bf(hi) << 16);
}
__device__ __forceinline__ uint4 pack8(float4 a, float4 b) {
    uint4 r;
    r.x = pack2(a.x, a.y);
    r.y = pack2(a.z, a.w);
    r.z = pack2(b.x, b.y);
    r.w = pack2(b.z, b.w);
    return r;
}

// Convert ONLY the gate-o block (rows 3H..4H of w_hh) to bf16: 32 MB output.
__global__ void convert_o_kernel(const float4* __restrict__ w,
                                 uint4* __restrict__ o, int n8) {
    int stride = gridDim.x * blockDim.x;
    for (int i = blockIdx.x * blockDim.x + threadIdx.x; i < n8; i += stride) {
        float4 a = w[2 * i];
        float4 b = w[2 * i + 1];
        o[i] = pack8(a, b);
    }
}

// Zero h0|h1|ctr region (contiguous dwords at start of ws; harness poisons ws).
__global__ void init_ws_kernel(unsigned* __restrict__ p, int n) {
    int i = blockIdx.x * blockDim.x + threadIdx.x;
    if (i < n) p[i] = 0u;
}

// ---------- helpers ----------
__device__ __forceinline__ float bflo(unsigned u) { return __uint_as_float(u << 16); }
__device__ __forceinline__ float bfhi(unsigned u) { return __uint_as_float(u & 0xffff0000u); }

__device__ __forceinline__ float dot8_bf(uint4 w, float4 ha, float4 hb, float acc) {
    acc = fmaf(bflo(w.x), ha.x, acc);
    acc = fmaf(bfhi(w.x), ha.y, acc);
    acc = fmaf(bflo(w.y), ha.z, acc);
    acc = fmaf(bfhi(w.y), ha.w, acc);
    acc = fmaf(bflo(w.z), hb.x, acc);
    acc = fmaf(bfhi(w.z), hb.y, acc);
    acc = fmaf(bflo(w.w), hb.z, acc);
    acc = fmaf(bfhi(w.w), hb.w, acc);
    return acc;
}

__device__ __forceinline__ float dot8_f32(float4 wa, float4 wb, float4 ha, float4 hb, float acc) {
    acc = fmaf(wa.x, ha.x, acc);
    acc = fmaf(wa.y, ha.y, acc);
    acc = fmaf(wa.z, ha.z, acc);
    acc = fmaf(wa.w, ha.w, acc);
    acc = fmaf(wb.x, hb.x, acc);
    acc = fmaf(wb.y, hb.y, acc);
    acc = fmaf(wb.z, hb.z, acc);
    acc = fmaf(wb.w, hb.w, acc);
    return acc;
}

__device__ __forceinline__ float sigm(float x) { return 1.0f / (1.0f + expf(-x)); }

// Stage the 16KB h vector into LDS: one 16B L2-bypassing (sc0 sc1 ->
// MALL-coherent) load per thread. Never reads a stale XCD-L2 line.
__device__ __forceinline__ void stage_h(float* __restrict__ hsh,
                                        const float* __restrict__ hsrc) {
    int base = threadIdx.x * 4;
    const float* p = hsrc + base;
    float4 v;
    asm volatile("global_load_dwordx4 %0, %1, off sc0 sc1\n\t"
                 "s_waitcnt vmcnt(0)"
                 : "=v"(v) : "v"(p) : "memory");
    *(float4*)(hsh + base) = v;
}

// ---------- persistent LSTM, weights on-chip (regs + LDS) + L2 stream ----------
// 256 blocks x 1024 threads = 4096 waves = one wave per hidden unit j.
// Per-wave weight partition (32 chunks of 1KB bf16 per unit):
//   gate i (8 chunks) + gate f (8 chunks)      -> 64 VGPRs/lane, persistent
//   gate g (8 chunks) + gate o chunk 0         -> 9 KB LDS/wave
//   gate o chunks 1..7                         -> streamed bf16, depth-2 prefetch
// LDS: h 16 KB + gateG 128 KB + gateO0 16 KB = 160 KB exactly.
// Streamed footprint: 7 KB/wave * 16 = 112 KB/CU -> 3.6 MB/XCD < 4 MB L2.
//
// REGISTER BUDGET (the R2/R3 failure): attributes placed between the return
// type and the declarator were silently ignored by clang -> VGPR cap stayed 64
// -> ~45 regs of spill/step -> 68-207 MB scratch writeback flushed to HBM by
// the barrier release each step. Fix: attribute list at the FRONT of plain
// (non-template) kernel declarations + amdgpu_num_vgpr(128) direct override.
// 16 waves/block at 1 block/CU = 4 waves/SIMD -> 512/4 = 128 VGPRs is legal.
template <bool STRB>
__device__ __forceinline__ void
lstm_body(const float* __restrict__ x,
          const float* __restrict__ w_ih,
          const float* __restrict__ b_ih,
          const float* __restrict__ b_hh,
          const float* __restrict__ w_hh,
          const unsigned short* __restrict__ obf,
          const float* __restrict__ dense_w,
          const float* __restrict__ dense_b,
          float* __restrict__ h0,
          float* __restrict__ h1,
          unsigned* __restrict__ ctr,
          float* __restrict__ out) {
    extern __shared__ float smem[];
    float* hsh   = smem;                          // [0,16K): 4096 f32
    uint4* ldsG  = (uint4*)(smem + HID);          // [16K,144K): 16w x 512 uint4
    uint4* ldsO0 = (uint4*)(smem + HID + 32768);  // [144K,160K): 16w x 64 uint4

    const int lane = threadIdx.x & 63;
    const int wv   = threadIdx.x >> 6;                 // wave in block, 0..15
    const int j    = (blockIdx.x << 4) | wv;           // hidden unit, 0..4095

    float wih0 = w_ih[0 * HID + j], bb0 = b_ih[0 * HID + j] + b_hh[0 * HID + j];
    float wih1 = w_ih[1 * HID + j], bb1 = b_ih[1 * HID + j] + b_hh[1 * HID + j];
    float wih2 = w_ih[2 * HID + j], bb2 = b_ih[2 * HID + j] + b_hh[2 * HID + j];
    float wih3 = w_ih[3 * HID + j], bb3 = b_ih[3 * HID + j] + b_hh[3 * HID + j];

    const float4* qi = (const float4*)(w_hh + (size_t)(0 * HID + j) * HID);
    const float4* qf = (const float4*)(w_hh + (size_t)(1 * HID + j) * HID);
    const float4* qg = (const float4*)(w_hh + (size_t)(2 * HID + j) * HID);
    const float4* qo = (const float4*)(w_hh + (size_t)(3 * HID + j) * HID);
    const uint4*  po = (const uint4*)(obf + (size_t)j * HID);

    // ---- prologue: load fp32 weights once, pack bf16 into regs + LDS ----
    uint4 wi[8], wf[8];
#pragma unroll
    for (int it = 0; it < 8; ++it) {
        int i0 = it * 128 + lane * 2;
        wi[it] = pack8(qi[i0], qi[i0 + 1]);
        wf[it] = pack8(qf[i0], qf[i0 + 1]);
        ldsG[wv * 512 + it * 64 + lane] = pack8(qg[i0], qg[i0 + 1]);
    }
    ldsO0[wv * 64 + lane] = pack8(qo[lane * 2], qo[lane * 2 + 1]);
    // No barrier needed for weight LDS: each wave writes/reads only its own
    // region; the per-step __syncthreads covers the h region.

    float c = 0.0f;

    for (int t = 0; t < SEQL; ++t) {
        const float* hr = (t & 1) ? h1 : h0;   // t=0 reads h0 (zeros from init)
        float*       hw = (t & 1) ? h0 : h1;

        // Issue the first streamed gate-o chunk BEFORE the h broadcast: its
        // L2 latency hides under stage_h's MALL-latency vmcnt(0) drain.
        uint4 onxt;
        if constexpr (STRB) {
            onxt = po[64 + lane];
        } else {
            int i0 = 128 + lane * 2;
            onxt = pack8(qo[i0], qo[i0 + 1]);
        }

        stage_h(hsh, hr);
        __syncthreads();

        const float4* hv = (const float4*)hsh;
        float xt = x[t];
        float acc0 = 0.f, acc1 = 0.f, acc2 = 0.f, acc3 = 0.f;

#pragma unroll
        for (int it = 0; it < 8; ++it) {
            float4 ha = hv[it * 128 + lane * 2];
            float4 hb = hv[it * 128 + lane * 2 + 1];
            uint4 cg = ldsG[wv * 512 + it * 64 + lane];
            uint4 ow = (it == 0) ? ldsO0[wv * 64 + lane] : onxt;
            if (it > 0 && it < 7) {  // depth-2 prefetch of next streamed chunk
                if constexpr (STRB) {
                    onxt = po[(it + 1) * 64 + lane];
                } else {
                    int i2 = (it + 1) * 128 + lane * 2;
                    onxt = pack8(qo[i2], qo[i2 + 1]);
                }
            }
            acc0 = dot8_bf(wi[it], ha, hb, acc0);
            acc1 = dot8_bf(wf[it], ha, hb, acc1);
            acc2 = dot8_bf(cg,     ha, hb, acc2);
            acc3 = dot8_bf(ow,     ha, hb, acc3);
        }

#pragma unroll
        for (int off = 32; off; off >>= 1) {
            acc0 += __shfl_xor(acc0, off, 64);
            acc1 += __shfl_xor(acc1, off, 64);
            acc2 += __shfl_xor(acc2, off, 64);
            acc3 += __shfl_xor(acc3, off, 64);
        }
        float gi = acc0 + wih0 * xt + bb0;
        float gf = acc1 + wih1 * xt + bb1;
        float gg = acc2 + wih2 * xt + bb2;
        float go = acc3 + wih3 * xt + bb3;
        c = sigm(gf) * c + sigm(gi) * tanhf(gg);
        float hn = sigm(go) * tanhf(c);
        if (lane == 0)
            __hip_atomic_store(hw + j, hn, __ATOMIC_RELAXED, __HIP_MEMORY_SCOPE_AGENT);

        // ---- hand-rolled device barrier for step t ----
        __syncthreads();
        if (threadIdx.x == 0) {
            __hip_atomic_fetch_add(ctr + t, 1u, __ATOMIC_RELEASE, __HIP_MEMORY_SCOPE_AGENT);
            while (__hip_atomic_load(ctr + t, __ATOMIC_RELAXED, __HIP_MEMORY_SCOPE_AGENT)
                   < (unsigned)NBLK)
                __builtin_amdgcn_s_sleep(2);
        }
        __syncthreads();
    }

    // Final h is in h0 (t=39 odd wrote hw=h0). Dense epilogue on blocks 0-7.
    if (blockIdx.x < OUTN / 16) {
        stage_h(hsh, h0);
        __syncthreads();
        const float4* hv  = (const float4*)hsh;
        const float4* dwr = (const float4*)(dense_w + (size_t)j * HID);
        float acc = 0.f;
#pragma unroll
        for (int it = 0; it < 8; ++it) {
            int i0 = it * 128 + lane * 2;
            acc = dot8_f32(dwr[i0], dwr[i0 + 1], hv[i0], hv[i0 + 1], acc);
        }
#pragma unroll
        for (int off = 32; off; off >>= 1) acc += __shfl_xor(acc, off, 64);
        if (lane == 0) out[j] = acc + dense_b[j];
    }
}

// Attributes at the FRONT of plain kernel declarations (canonical position).
__attribute__((amdgpu_flat_work_group_size(1024, 1024),
               amdgpu_waves_per_eu(4, 4),
               amdgpu_num_vgpr(128)))
__global__ void
lstm_kernel_bf(const float* __restrict__ x,
               const float* __restrict__ w_ih,
               const float* __restrict__ b_ih,
               const float* __restrict__ b_hh,
               const float* __restrict__ w_hh,
               const unsigned short* __restrict__ obf,
               const float* __restrict__ dense_w,
               const float* __restrict__ dense_b,
               float* __restrict__ h0,
               float* __restrict__ h1,
               unsigned* __restrict__ ctr,
               float* __restrict__ out) {
    lstm_body<true>(x, w_ih, b_ih, b_hh, w_hh, obf, dense_w, dense_b,
                    h0, h1, ctr, out);
}

__attribute__((amdgpu_flat_work_group_size(1024, 1024),
               amdgpu_waves_per_eu(4, 4),
               amdgpu_num_vgpr(128)))
__global__ void
lstm_kernel_f32(const float* __restrict__ x,
                const float* __restrict__ w_ih,
                const float* __restrict__ b_ih,
                const float* __restrict__ b_hh,
                const float* __restrict__ w_hh,
                const unsigned short* __restrict__ obf,
                const float* __restrict__ dense_w,
                const float* __restrict__ dense_b,
                float* __restrict__ h0,
                float* __restrict__ h1,
                unsigned* __restrict__ ctr,
                float* __restrict__ out) {
    lstm_body<false>(x, w_ih, b_ih, b_hh, w_hh, obf, dense_w, dense_b,
                     h0, h1, ctr, out);
}

extern "C" void kernel_launch(void* const* d_in, const int* in_sizes, int n_in,
                              void* d_out, int out_size, void* d_ws, size_t ws_size,
                              hipStream_t stream) {
    const float* x       = (const float*)d_in[0];
    const float* w_ih    = (const float*)d_in[1];
    const float* w_hh    = (const float*)d_in[2];
    const float* b_ih    = (const float*)d_in[3];
    const float* b_hh    = (const float*)d_in[4];
    const float* dense_w = (const float*)d_in[5];
    const float* dense_b = (const float*)d_in[6];
    float* out = (float*)d_out;

    // ws layout: h0[4096] f32 | h1[4096] f32 | ctr[64] u32 | obf bf16[H*H] (32MB)
    float*    h0  = (float*)d_ws;
    float*    h1  = h0 + HID;
    unsigned* ctr = (unsigned*)(h1 + HID);
    unsigned short* obf = (unsigned short*)(ctr + 64);

    // Zero h0|h1|ctr (contiguous 2*HID + 64 dwords; harness poisons ws).
    int nz = 2 * HID + 64;
    init_ws_kernel<<<(nz + 1023) / 1024, 1024, 0, stream>>>((unsigned*)d_ws, nz);

    size_t need = (size_t)(2 * HID + 64) * 4 + (size_t)HID * HID * sizeof(unsigned short);
    bool strb = ws_size >= need;

    static int smem_attr_set = 0;
    if (!smem_attr_set) {
        hipFuncSetAttribute((void*)lstm_kernel_bf,
                            hipFuncAttributeMaxDynamicSharedMemorySize, 160 * 1024);
        hipFuncSetAttribute((void*)lstm_kernel_f32,
                            hipFuncAttributeMaxDynamicSharedMemorySize, 160 * 1024);
        smem_attr_set = 1;
    }

    if (strb) {
        // convert gate-o rows (3H..4H) to bf16 once
        int n8 = HID * HID / 8;
        convert_o_kernel<<<2048, 256, 0, stream>>>(
            (const float4*)(w_hh + (size_t)3 * HID * HID), (uint4*)obf, n8);
        void* args[] = {(void*)&x, (void*)&w_ih, (void*)&b_ih, (void*)&b_hh,
                        (void*)&w_hh, (void*)&obf, (void*)&dense_w, (void*)&dense_b,
                        (void*)&h0, (void*)&h1, (void*)&ctr, (void*)&out};
        hipLaunchCooperativeKernel((void*)lstm_kernel_bf, dim3(NBLK), dim3(1024),
                                   args, 160 * 1024, stream);
    } else {
        void* args[] = {(void*)&x, (void*)&w_ih, (void*)&b_ih, (void*)&b_hh,
                        (void*)&w_hh, (void*)&obf, (void*)&dense_w, (void*)&dense_b,
                        (void*)&h0, (void*)&h1, (void*)&ctr, (void*)&out};
        hipLaunchCooperativeKernel((void*)lstm_kernel_f32, dim3(NBLK), dim3(1024),
                                   args, 160 * 1024, stream);
    }
}

// Round 6
// 1465.367 us; speedup vs baseline: 1.0779x; 1.0779x over previous
//
#include <hip/hip_runtime.h>

static constexpr int HID    = 4096;  // hidden size
static constexpr int SEQL   = 40;
static constexpr int OUTN   = 128;
static constexpr int NBLK_P = 1024;  // primary: 1024 blocks x 256 thr (4/CU)
static constexpr int NBLK_F = 256;   // fallback: 256 blocks x 1024 thr (1/CU)

// ---------- fp32 -> bf16 (RNE) ----------
__device__ __forceinline__ unsigned f2bf(float f) {
    unsigned u = __float_as_uint(f);
    return (u + 0x7fffu + ((u >> 16) & 1u)) >> 16;
}
__device__ __forceinline__ unsigned pack2(float lo, float hi) {
    return f2bf(lo) | (f2bf(hi) << 16);
}
__device__ __forceinline__ uint4 pack8(float4 a, float4 b) {
    uint4 r;
    r.x = pack2(a.x, a.y);
    r.y = pack2(a.z, a.w);
    r.z = pack2(b.x, b.y);
    r.w = pack2(b.z, b.w);
    return r;
}

// Generic fp32->bf16 block converter (8 elems / thread-iter).
__global__ void convert_w_kernel(const float4* __restrict__ w,
                                 uint4* __restrict__ o, int n8) {
    int stride = gridDim.x * blockDim.x;
    for (int i = blockIdx.x * blockDim.x + threadIdx.x; i < n8; i += stride) {
        float4 a = w[2 * i];
        float4 b = w[2 * i + 1];
        o[i] = pack8(a, b);
    }
}

// Zero h0|h1|ctr region (harness poisons ws; monotonic barrier needs zeros).
__global__ void init_ws_kernel(unsigned* __restrict__ p, int n) {
    int i = blockIdx.x * blockDim.x + threadIdx.x;
    if (i < n) p[i] = 0u;
}

// ---------- helpers ----------
__device__ __forceinline__ float bflo(unsigned u) { return __uint_as_float(u << 16); }
__device__ __forceinline__ float bfhi(unsigned u) { return __uint_as_float(u & 0xffff0000u); }

__device__ __forceinline__ float dot8_bf(uint4 w, float4 ha, float4 hb, float acc) {
    acc = fmaf(bflo(w.x), ha.x, acc);
    acc = fmaf(bfhi(w.x), ha.y, acc);
    acc = fmaf(bflo(w.y), ha.z, acc);
    acc = fmaf(bfhi(w.y), ha.w, acc);
    acc = fmaf(bflo(w.z), hb.x, acc);
    acc = fmaf(bfhi(w.z), hb.y, acc);
    acc = fmaf(bflo(w.w), hb.z, acc);
    acc = fmaf(bfhi(w.w), hb.w, acc);
    return acc;
}

__device__ __forceinline__ float dot8_f32(float4 wa, float4 wb, float4 ha, float4 hb, float acc) {
    acc = fmaf(wa.x, ha.x, acc);
    acc = fmaf(wa.y, ha.y, acc);
    acc = fmaf(wa.z, ha.z, acc);
    acc = fmaf(wa.w, ha.w, acc);
    acc = fmaf(wb.x, hb.x, acc);
    acc = fmaf(wb.y, hb.y, acc);
    acc = fmaf(wb.z, hb.z, acc);
    acc = fmaf(wb.w, hb.w, acc);
    return acc;
}

__device__ __forceinline__ float sigm(float x) { return 1.0f / (1.0f + expf(-x)); }

// h broadcast into LDS, 1024-thread version: one 16B MALL-coherent load/thread.
__device__ __forceinline__ void stage_h(float* __restrict__ hsh,
                                        const float* __restrict__ hsrc) {
    int base = threadIdx.x * 4;
    const float* p = hsrc + base;
    float4 v;
    asm volatile("global_load_dwordx4 %0, %1, off sc0 sc1\n\t"
                 "s_waitcnt vmcnt(0)"
                 : "=v"(v) : "v"(p) : "memory");
    *(float4*)(hsh + base) = v;
}

// h broadcast into LDS, 256-thread version: 4 x 16B MALL-coherent loads/thread.
__device__ __forceinline__ void stage_h4(float* __restrict__ hsh,
                                         const float* __restrict__ hsrc) {
    int t0 = threadIdx.x * 4;
    const float* p0 = hsrc + t0;
    const float* p1 = hsrc + t0 + 1024;
    const float* p2 = hsrc + t0 + 2048;
    const float* p3 = hsrc + t0 + 3072;
    float4 a, b, c, d;
    asm volatile("global_load_dwordx4 %0, %4, off sc0 sc1\n\t"
                 "global_load_dwordx4 %1, %5, off sc0 sc1\n\t"
                 "global_load_dwordx4 %2, %6, off sc0 sc1\n\t"
                 "global_load_dwordx4 %3, %7, off sc0 sc1\n\t"
                 "s_waitcnt vmcnt(0)"
                 : "=&v"(a), "=&v"(b), "=&v"(c), "=&v"(d)
                 : "v"(p0), "v"(p1), "v"(p2), "v"(p3)
                 : "memory");
    *(float4*)(hsh + t0)        = a;
    *(float4*)(hsh + t0 + 1024) = b;
    *(float4*)(hsh + t0 + 2048) = c;
    *(float4*)(hsh + t0 + 3072) = d;
}

// ======================= PRIMARY: 1024 x 256 =======================
// One wave per hidden unit. Per-wave weight partition (32 x 1KB bf16 chunks):
//   gates i,f (16 chunks)        -> 64 persistent VGPRs/lane
//   gate g chunks 2..7           -> 6 KB/wave LDS (24 KB/block)
//   gate g chunks 0,1 + gate o   -> streamed bf16, 4-slot distance-2 prefetch
// LDS/block: h 16 KB + gateG 24 KB = 40 KB -> 4 blocks/CU co-resident.
// Stream: 10 KB/unit/step -> 160 KB/CU -> ~5 MB/XCD: L2-resident + MALL slack.
// Barrier: monotonic two-level (8 groups x 128 blocks), 128B-separated lines,
// acquire-poll; no per-step counters, zeroed once at init.
__global__ void __launch_bounds__(256, 4)
lstm_small(const float* __restrict__ x,
           const float* __restrict__ w_ih,
           const float* __restrict__ b_ih,
           const float* __restrict__ b_hh,
           const float* __restrict__ w_hh,
           const unsigned short* __restrict__ wbf,  // full 4HH layout; rows 2H..4H valid
           const float* __restrict__ dense_w,
           const float* __restrict__ dense_b,
           float* __restrict__ h0,
           float* __restrict__ h1,
           unsigned* __restrict__ ctr,
           float* __restrict__ out) {
    extern __shared__ float smem[];
    float* hsh  = smem;                  // [0,16K): 4096 f32
    uint4* ldsG = (uint4*)(smem + HID);  // [16K,40K): 4 waves x 6 chunks x 64

    const int lane = threadIdx.x & 63;
    const int wv   = threadIdx.x >> 6;           // wave in block, 0..3
    const int j    = (blockIdx.x << 2) | wv;     // hidden unit, 0..4095

    float wih0 = w_ih[0 * HID + j], bb0 = b_ih[0 * HID + j] + b_hh[0 * HID + j];
    float wih1 = w_ih[1 * HID + j], bb1 = b_ih[1 * HID + j] + b_hh[1 * HID + j];
    float wih2 = w_ih[2 * HID + j], bb2 = b_ih[2 * HID + j] + b_hh[2 * HID + j];
    float wih3 = w_ih[3 * HID + j], bb3 = b_ih[3 * HID + j] + b_hh[3 * HID + j];

    const float4* qi = (const float4*)(w_hh + (size_t)(0 * HID + j) * HID);
    const float4* qf = (const float4*)(w_hh + (size_t)(1 * HID + j) * HID);
    const float4* qg = (const float4*)(w_hh + (size_t)(2 * HID + j) * HID);
    const uint4*  pg = (const uint4*)(wbf + (size_t)(2 * HID + j) * HID);
    const uint4*  po = (const uint4*)(wbf + (size_t)(3 * HID + j) * HID);

    // ---- prologue: i,f chunks into regs; g chunks 2..7 into LDS ----
    uint4 wi[8], wf[8];
#pragma unroll
    for (int it = 0; it < 8; ++it) {
        int i0 = it * 128 + lane * 2;
        wi[it] = pack8(qi[i0], qi[i0 + 1]);
        wf[it] = pack8(qf[i0], qf[i0 + 1]);
        if (it >= 2)
            ldsG[(wv * 6 + (it - 2)) * 64 + lane] = pack8(qg[i0], qg[i0 + 1]);
    }
    // Weight LDS is per-wave private (write+read by the same wave only).

    float c = 0.0f;

#define DOT_IT(IT, CG, OW)                                      \
    {                                                           \
        float4 ha = hv[(IT) * 128 + lane * 2];                  \
        float4 hb = hv[(IT) * 128 + lane * 2 + 1];              \
        acc0 = dot8_bf(wi[IT], ha, hb, acc0);                   \
        acc1 = dot8_bf(wf[IT], ha, hb, acc1);                   \
        acc2 = dot8_bf((CG), ha, hb, acc2);                     \
        acc3 = dot8_bf((OW), ha, hb, acc3);                     \
    }

    for (int t = 0; t < SEQL; ++t) {
        const float* hr = (t & 1) ? h1 : h0;   // t=0 reads h0 (zeros)
        float*       hw = (t & 1) ? h0 : h1;

        // Pre-issue 4 stream slots (g0,g1,o0,o1) BEFORE the h broadcast so
        // their latency hides under stage_h4's vmcnt(0) drain.
        uint4 sA = pg[lane];            // g0
        uint4 sB = pg[64 + lane];       // g1
        uint4 sC = po[lane];            // o0
        uint4 sD = po[64 + lane];       // o1

        stage_h4(hsh, hr);
        __syncthreads();

        const float4* hv = (const float4*)hsh;
        float xt = x[t];
        float acc0 = 0.f, acc1 = 0.f, acc2 = 0.f, acc3 = 0.f;

        // Fully unrolled; named slots, distance-2 refills (no runtime-indexed
        // arrays -> no scratch).
        DOT_IT(0, sA, sC);  sA = po[2 * 64 + lane];               // o2
        DOT_IT(1, sB, sD);  sB = po[3 * 64 + lane];               // o3
                            sC = po[4 * 64 + lane];               // o4
        DOT_IT(2, ldsG[(wv * 6 + 0) * 64 + lane], sA);
                            sD = po[5 * 64 + lane];               // o5
        DOT_IT(3, ldsG[(wv * 6 + 1) * 64 + lane], sB);
                            sA = po[6 * 64 + lane];               // o6
        DOT_IT(4, ldsG[(wv * 6 + 2) * 64 + lane], sC);
                            sB = po[7 * 64 + lane];               // o7
        DOT_IT(5, ldsG[(wv * 6 + 3) * 64 + lane], sD);
        DOT_IT(6, ldsG[(wv * 6 + 4) * 64 + lane], sA);
        DOT_IT(7, ldsG[(wv * 6 + 5) * 64 + lane], sB);

#pragma unroll
        for (int off = 32; off; off >>= 1) {
            acc0 += __shfl_xor(acc0, off, 64);
            acc1 += __shfl_xor(acc1, off, 64);
            acc2 += __shfl_xor(acc2, off, 64);
            acc3 += __shfl_xor(acc3, off, 64);
        }
        float gi = acc0 + wih0 * xt + bb0;
        float gf = acc1 + wih1 * xt + bb1;
        float gg = acc2 + wih2 * xt + bb2;
        float go = acc3 + wih3 * xt + bb3;
        c = sigm(gf) * c + sigm(gi) * tanhf(gg);
        float hn = sigm(go) * tanhf(c);
        if (lane == 0)
            __hip_atomic_store(hw + j, hn, __ATOMIC_RELAXED, __HIP_MEMORY_SCOPE_AGENT);

        // ---- monotonic two-level device barrier ----
        // __syncthreads drains this block's h-stores (vmcnt(0) before
        // s_barrier). Group counter at 128B-separated lines; the 128*(t+1)-th
        // arriver promotes the top counter; all poll top == 8*(t+1).
        __syncthreads();
        if (threadIdx.x == 0) {
            unsigned* la = ctr + ((unsigned)blockIdx.x >> 7) * 32;
            unsigned* lb = ctr + 256;
            unsigned v = __hip_atomic_fetch_add(la, 1u, __ATOMIC_RELEASE,
                                                __HIP_MEMORY_SCOPE_AGENT) + 1u;
            if (v == 128u * (unsigned)(t + 1))
                __hip_atomic_fetch_add(lb, 1u, __ATOMIC_RELEASE,
                                       __HIP_MEMORY_SCOPE_AGENT);
            while (__hip_atomic_load(lb, __ATOMIC_ACQUIRE,
                                     __HIP_MEMORY_SCOPE_AGENT)
                   < 8u * (unsigned)(t + 1))
                __builtin_amdgcn_s_sleep(2);
        }
        __syncthreads();
    }

    // Final h is in h0 (t=39 odd wrote hw=h0). Dense epilogue on blocks 0-31.
    if (blockIdx.x < OUTN / 4) {
        stage_h4(hsh, h0);
        __syncthreads();
        const float4* hv  = (const float4*)hsh;
        const float4* dwr = (const float4*)(dense_w + (size_t)j * HID);
        float acc = 0.f;
#pragma unroll
        for (int it = 0; it < 8; ++it) {
            int i0 = it * 128 + lane * 2;
            acc = dot8_f32(dwr[i0], dwr[i0 + 1], hv[i0], hv[i0 + 1], acc);
        }
#pragma unroll
        for (int off = 32; off; off >>= 1) acc += __shfl_xor(acc, off, 64);
        if (lane == 0) out[j] = acc + dense_b[j];
    }
#undef DOT_IT
}

// ======================= FALLBACK: 256 x 1024 (R1, proven) =======================
template <bool BF16>
__global__ void __launch_bounds__(1024, 4)
lstm_big(const float* __restrict__ x,
         const float* __restrict__ w_ih,
         const float* __restrict__ b_ih,
         const float* __restrict__ b_hh,
         const void*  __restrict__ whh,
         const float* __restrict__ dense_w,
         const float* __restrict__ dense_b,
         float* __restrict__ h0,
         float* __restrict__ h1,
         unsigned* __restrict__ ctr,
         float* __restrict__ out) {
    __shared__ float hsh[HID];  // 16 KB staged h
    const int lane = threadIdx.x & 63;
    const int j = (blockIdx.x << 4) | (threadIdx.x >> 6);  // hidden unit

    float wih0 = w_ih[0 * HID + j], bb0 = b_ih[0 * HID + j] + b_hh[0 * HID + j];
    float wih1 = w_ih[1 * HID + j], bb1 = b_ih[1 * HID + j] + b_hh[1 * HID + j];
    float wih2 = w_ih[2 * HID + j], bb2 = b_ih[2 * HID + j] + b_hh[2 * HID + j];
    float wih3 = w_ih[3 * HID + j], bb3 = b_ih[3 * HID + j] + b_hh[3 * HID + j];

    const uint4*  p0 = nullptr, *p1 = nullptr, *p2 = nullptr, *p3 = nullptr;
    const float4* q0 = nullptr, *q1 = nullptr, *q2 = nullptr, *q3 = nullptr;
    if constexpr (BF16) {
        p0 = (const uint4*)((const unsigned short*)whh + (size_t)(0 * HID + j) * HID);
        p1 = (const uint4*)((const unsigned short*)whh + (size_t)(1 * HID + j) * HID);
        p2 = (const uint4*)((const unsigned short*)whh + (size_t)(2 * HID + j) * HID);
        p3 = (const uint4*)((const unsigned short*)whh + (size_t)(3 * HID + j) * HID);
    } else {
        q0 = (const float4*)((const float*)whh + (size_t)(0 * HID + j) * HID);
        q1 = (const float4*)((const float*)whh + (size_t)(1 * HID + j) * HID);
        q2 = (const float4*)((const float*)whh + (size_t)(2 * HID + j) * HID);
        q3 = (const float4*)((const float*)whh + (size_t)(3 * HID + j) * HID);
    }

    float c = 0.0f;

    for (int t = 0; t < SEQL; ++t) {
        const float* hr = (t & 1) ? h1 : h0;
        float*       hw = (t & 1) ? h0 : h1;

        uint4 w0, w1, w2, w3;
        if constexpr (BF16) {
            w0 = p0[lane]; w1 = p1[lane]; w2 = p2[lane]; w3 = p3[lane];
        }

        stage_h(hsh, hr);
        __syncthreads();

        const float4* hv = (const float4*)hsh;
        float xt = x[t];
        float acc0 = 0.f, acc1 = 0.f, acc2 = 0.f, acc3 = 0.f;

        if constexpr (BF16) {
#pragma unroll
            for (int it = 0; it < 8; ++it) {
                uint4 c0 = w0, c1 = w1, c2 = w2, c3 = w3;
                if (it < 7) {
                    int ni = (it + 1) * 64 + lane;
                    w0 = p0[ni]; w1 = p1[ni]; w2 = p2[ni]; w3 = p3[ni];
                }
                float4 ha = hv[it * 128 + lane * 2];
                float4 hb = hv[it * 128 + lane * 2 + 1];
                acc0 = dot8_bf(c0, ha, hb, acc0);
                acc1 = dot8_bf(c1, ha, hb, acc1);
                acc2 = dot8_bf(c2, ha, hb, acc2);
                acc3 = dot8_bf(c3, ha, hb, acc3);
            }
        } else {
#pragma unroll
            for (int it = 0; it < 8; ++it) {
                int i0 = it * 128 + lane * 2;
                float4 ha = hv[i0], hb = hv[i0 + 1];
                acc0 = dot8_f32(q0[i0], q0[i0 + 1], ha, hb, acc0);
                acc1 = dot8_f32(q1[i0], q1[i0 + 1], ha, hb, acc1);
                acc2 = dot8_f32(q2[i0], q2[i0 + 1], ha, hb, acc2);
                acc3 = dot8_f32(q3[i0], q3[i0 + 1], ha, hb, acc3);
            }
        }

#pragma unroll
        for (int off = 32; off; off >>= 1) {
            acc0 += __shfl_xor(acc0, off, 64);
            acc1 += __shfl_xor(acc1, off, 64);
            acc2 += __shfl_xor(acc2, off, 64);
            acc3 += __shfl_xor(acc3, off, 64);
        }
        float gi = acc0 + wih0 * xt + bb0;
        float gf = acc1 + wih1 * xt + bb1;
        float gg = acc2 + wih2 * xt + bb2;
        float go = acc3 + wih3 * xt + bb3;
        c = sigm(gf) * c + sigm(gi) * tanhf(gg);
        float hn = sigm(go) * tanhf(c);
        if (lane == 0)
            __hip_atomic_store(hw + j, hn, __ATOMIC_RELAXED, __HIP_MEMORY_SCOPE_AGENT);

        __syncthreads();
        if (threadIdx.x == 0) {
            __hip_atomic_fetch_add(ctr + t, 1u, __ATOMIC_RELEASE, __HIP_MEMORY_SCOPE_AGENT);
            while (__hip_atomic_load(ctr + t, __ATOMIC_RELAXED, __HIP_MEMORY_SCOPE_AGENT)
                   < (unsigned)NBLK_F)
                __builtin_amdgcn_s_sleep(2);
        }
        __syncthreads();
    }

    if (blockIdx.x < OUTN / 16) {
        stage_h(hsh, h0);
        __syncthreads();
        const float4* hv  = (const float4*)hsh;
        const float4* dwr = (const float4*)(dense_w + (size_t)j * HID);
        float acc = 0.f;
#pragma unroll
        for (int it = 0; it < 8; ++it) {
            int i0 = it * 128 + lane * 2;
            acc = dot8_f32(dwr[i0], dwr[i0 + 1], hv[i0], hv[i0 + 1], acc);
        }
#pragma unroll
        for (int off = 32; off; off >>= 1) acc += __shfl_xor(acc, off, 64);
        if (lane == 0) out[j] = acc + dense_b[j];
    }
}

extern "C" void kernel_launch(void* const* d_in, const int* in_sizes, int n_in,
                              void* d_out, int out_size, void* d_ws, size_t ws_size,
                              hipStream_t stream) {
    const float* x       = (const float*)d_in[0];
    const float* w_ih    = (const float*)d_in[1];
    const float* w_hh    = (const float*)d_in[2];
    const float* b_ih    = (const float*)d_in[3];
    const float* b_hh    = (const float*)d_in[4];
    const float* dense_w = (const float*)d_in[5];
    const float* dense_b = (const float*)d_in[6];
    float* out = (float*)d_out;

    // ws: h0[4096] | h1[4096] | ctr[512] (primary A:0..255, B:256; fallback
    // flat:320..359) | wbf bf16[4*H*H] (full gate layout, 128 MB)
    float*    h0   = (float*)d_ws;
    float*    h1   = h0 + HID;
    unsigned* ctr  = (unsigned*)(h1 + HID);
    unsigned* ctrF = ctr + 320;
    unsigned short* wbf = (unsigned short*)(ctr + 512);

    int nz = 2 * HID + 512;
    init_ws_kernel<<<(nz + 1023) / 1024, 1024, 0, stream>>>((unsigned*)d_ws, nz);

    size_t need = (size_t)nz * 4 + (size_t)4 * HID * HID * sizeof(unsigned short);
    bool bf = ws_size >= need;

    static int attr_set = 0;
    if (!attr_set) {
        hipFuncSetAttribute((void*)lstm_small,
                            hipFuncAttributeMaxDynamicSharedMemorySize, 40 * 1024);
        attr_set = 1;
    }

    bool primary_done = false;
    if (bf) {
        int nb = 0;
        hipError_t qrc = hipOccupancyMaxActiveBlocksPerMultiprocessor(
            &nb, (const void*)lstm_small, 256, 40 * 1024);
        if (qrc == hipSuccess && nb >= 4) {
            // convert gate g,o rows (2H..4H) into the matching wbf region
            int n8 = 2 * HID * HID / 8;
            convert_w_kernel<<<2048, 256, 0, stream>>>(
                (const float4*)(w_hh + (size_t)2 * HID * HID),
                (uint4*)(wbf + (size_t)2 * HID * HID), n8);
            void* args[] = {(void*)&x, (void*)&w_ih, (void*)&b_ih, (void*)&b_hh,
                            (void*)&w_hh, (void*)&wbf, (void*)&dense_w,
                            (void*)&dense_b, (void*)&h0, (void*)&h1,
                            (void*)&ctr, (void*)&out};
            hipError_t rc = hipLaunchCooperativeKernel(
                (void*)lstm_small, dim3(NBLK_P), dim3(256), args, 40 * 1024, stream);
            if (rc == hipSuccess) primary_done = true;
        }
    }

    if (!primary_done) {
        if (bf) {
            int n8 = 4 * HID * HID / 8;
            convert_w_kernel<<<2048, 256, 0, stream>>>(
                (const float4*)w_hh, (uint4*)wbf, n8);
            const void* wptr = (const void*)wbf;
            void* args[] = {(void*)&x, (void*)&w_ih, (void*)&b_ih, (void*)&b_hh,
                            (void*)&wptr, (void*)&dense_w, (void*)&dense_b,
                            (void*)&h0, (void*)&h1, (void*)&ctrF, (void*)&out};
            hipLaunchCooperativeKernel((void*)lstm_big<true>, dim3(NBLK_F),
                                       dim3(1024), args, 0, stream);
        } else {
            const void* wptr = (const void*)w_hh;
            void* args[] = {(void*)&x, (void*)&w_ih, (void*)&b_ih, (void*)&b_hh,
                            (void*)&wptr, (void*)&dense_w, (void*)&dense_b,
                            (void*)&h0, (void*)&h1, (void*)&ctrF, (void*)&out};
            hipLaunchCooperativeKernel((void*)lstm_big<false>, dim3(NBLK_F),
                                       dim3(1024), args, 0, stream);
        }
    }
}